// Round 15
// baseline (213.552 us; speedup 1.0000x reference)
//
#include <hip/hip_runtime.h>
#include <math.h>

#define N_NODES 50000
#define N_EDGES 400000
#define NPAD    50176            // 196*256
#define MROWS   50048            // 782*64, padded row count for gemm outputs
#define HC0 128
#define HC1 256
#define CSR_TOTAL (N_NODES + N_EDGES)   // 450000 records + 64 tail pad
#define EB 1563                  // edge blocks (1563*256 >= 400000)
#define NB 196                   // node blocks (196*256 >= 50000)
#define PB 480                   // pack blocks (480*2 = 960 BT rows-groups)

typedef short    bf16x8 __attribute__((ext_vector_type(8)));
typedef float    f32x4  __attribute__((ext_vector_type(4)));
typedef _Float16 h2     __attribute__((ext_vector_type(2)));
typedef _Float16 h4     __attribute__((ext_vector_type(4)));
typedef _Float16 h8     __attribute__((ext_vector_type(8)));

__device__ inline unsigned short f2bf(float f) {
  union { float f; unsigned u; } v; v.f = f;
  unsigned r = v.u + 0x7FFFu + ((v.u >> 16) & 1u);   // RNE
  return (unsigned short)(r >> 16);
}
__device__ inline h2 mkh2(float a, float b) {
  h2 r; r[0] = (_Float16)a; r[1] = (_Float16)b; return r;
}
__device__ inline float hdot2(h2 a, h2 b, float c) {
#if __has_builtin(__builtin_amdgcn_fdot2)
  return __builtin_amdgcn_fdot2(a, b, c, false);
#else
  return c + (float)a[0] * (float)b[0] + (float)a[1] * (float)b[1];
#endif
}

// ---------------------------------------------------------------------------
// CSR build stage 1: degree histogram + weight sums
// ---------------------------------------------------------------------------
__global__ void deg_kernel(const int* __restrict__ ei, const float* __restrict__ ew,
                           float* __restrict__ s, int* __restrict__ deg) {
  int e = blockIdx.x * 256 + threadIdx.x;
  if (e < N_EDGES) {
    int dst = ei[N_EDGES + e];
    atomicAdd(&s[dst], ew[e]);
    atomicAdd(&deg[dst], 1);
  }
}

__global__ void scan1(const int* __restrict__ deg, int* __restrict__ part,
                      int* __restrict__ bsum) {
  int i = blockIdx.x * 256 + threadIdx.x;
  int lane = threadIdx.x & 63, wid = threadIdx.x >> 6;
  int v = (i < N_NODES) ? deg[i] + 1 : 0;
  int inc = v;
#pragma unroll
  for (int d = 1; d < 64; d <<= 1) { int y = __shfl_up(inc, d, 64); if (lane >= d) inc += y; }
  __shared__ int wsum[4];
  if (lane == 63) wsum[wid] = inc;
  __syncthreads();
  int off = 0;
#pragma unroll
  for (int w = 0; w < 4; ++w) { int sv = wsum[w]; if (w < wid) off += sv; }
  part[i] = inc - v + off;
  if (threadIdx.x == 0) bsum[blockIdx.x] = wsum[0] + wsum[1] + wsum[2] + wsum[3];
}

__global__ void scan2(int* __restrict__ bsum) {
  int t = threadIdx.x;
  int lane = t & 63, wid = t >> 6;
  int v = (t < 196) ? bsum[t] : 0;
  int inc = v;
#pragma unroll
  for (int d = 1; d < 64; d <<= 1) { int y = __shfl_up(inc, d, 64); if (lane >= d) inc += y; }
  __shared__ int wsum[4];
  if (lane == 63) wsum[wid] = inc;
  __syncthreads();
  int off = 0;
#pragma unroll
  for (int w = 0; w < 4; ++w) { int sv = wsum[w]; if (w < wid) off += sv; }
  if (t < 196) bsum[t] = inc - v + off;
}

// ---------------------------------------------------------------------------
// Fused build: edge scatter | self loops + tail zero | weight pack.
// ---------------------------------------------------------------------------
__global__ void fused_build(const int* __restrict__ ei, const float* __restrict__ ew,
                            const float* __restrict__ s, const int* __restrict__ deg,
                            const int* __restrict__ part, const int* __restrict__ bsum,
                            int* __restrict__ cursor, int2* __restrict__ csr2,
                            const float* __restrict__ Wl0, const float* __restrict__ Wr0,
                            const float* __restrict__ P0,  const float* __restrict__ Wl1,
                            const float* __restrict__ Wr1, const float* __restrict__ P1,
                            unsigned short* __restrict__ o_wl0, unsigned short* __restrict__ o_wr0,
                            unsigned short* __restrict__ o_p0,  unsigned short* __restrict__ o_wl1,
                            unsigned short* __restrict__ o_wr1, unsigned short* __restrict__ o_p1) {
  const int bid = blockIdx.x;
  if (bid < EB) {                       // ---- edge scatter
    int e = bid * 256 + threadIdx.x;
    if (e >= N_EDGES) return;
    int dst = ei[N_EDGES + e];
    int pos = atomicAdd(&cursor[dst], 1);
    int idx = part[dst] + bsum[dst >> 8] + 1 + pos;
    csr2[idx] = make_int2(ei[e], __float_as_int(ew[e]));
  } else if (bid < EB + NB) {           // ---- self loops + tail zero
    int i = (bid - EB) * 256 + threadIdx.x;
    if (i < N_NODES) {
      float w = s[i] / fmaxf((float)deg[i], 1.0f);
      int start = part[i] + bsum[i >> 8];
      csr2[start] = make_int2(i, __float_as_int(w));
    } else if (i - N_NODES < 64) {
      csr2[CSR_TOTAL + (i - N_NODES)] = make_int2(0, 0);
    }
  } else {                              // ---- weight pack (2 rows/block)
    int n = (bid - EB - NB) * 2 + (threadIdx.x >> 7);
    int k = threadIdx.x & 127;
    const float* W; unsigned short* O; int N, nl;
    if      (n < 128) { W = Wl0; O = o_wl0; N = 128; nl = n; }
    else if (n < 256) { W = Wr0; O = o_wr0; N = 128; nl = n - 128; }
    else if (n < 384) { W = P0;  O = o_p0;  N = 128; nl = n - 256; }
    else if (n < 640) { W = Wl1; O = o_wl1; N = 256; nl = n - 384; }
    else if (n < 896) { W = Wr1; O = o_wr1; N = 256; nl = n - 640; }
    else              { W = P1;  O = o_p1;  N = 64;  nl = n - 896; }
    O[nl * 128 + k] = f2bf(W[(size_t)k * N + nl]);
  }
}

// ---------------------------------------------------------------------------
// Merged GEMM layer 0: reads x fp32 (stages bf16 to LDS), outputs xl/xr/hres f16.
// ---------------------------------------------------------------------------
__global__ __launch_bounds__(256) void gemm_l0(
    const float* __restrict__ X, const unsigned short* __restrict__ BT,
    const float* __restrict__ bias0, const float* __restrict__ bias1,
    const float* __restrict__ bias2,
    _Float16* __restrict__ o_xl, _Float16* __restrict__ o_xr,
    _Float16* __restrict__ o_h, int M) {
  __shared__ unsigned short As[64 * 136];   // 272B pitch
  const int tid = threadIdx.x;
  const int rbase = blockIdx.x * 64;
#pragma unroll
  for (int i = 0; i < 8; ++i) {
    int c = i * 256 + tid;
    int row = c >> 5, c4 = c & 31;
    int ar = rbase + row; if (ar > M - 1) ar = M - 1;
    float4 v = *(const float4*)(X + (size_t)ar * 128 + c4 * 4);
    ushort4 o; o.x = f2bf(v.x); o.y = f2bf(v.y); o.z = f2bf(v.z); o.w = f2bf(v.w);
    *(ushort4*)(As + row * 136 + c4 * 4) = o;
  }
  __syncthreads();
  const int w = tid >> 6, l = tid & 63;
  const int lr = l & 15, lg = l >> 4;
#pragma unroll
  for (int i = 0; i < 6; ++i) {
    const int ct = w * 6 + i;
    const bf16x8* bp = (const bf16x8*)(BT + (size_t)(ct * 16 + lr) * 128 + lg * 8);
    bf16x8 b0 = bp[0], b1 = bp[4], b2 = bp[8], b3 = bp[12];
    const int colb = ct * 16 + lg * 4;
    const int cc = colb & 127;
    const float* bptr = (ct < 8 ? bias0 : (ct < 16 ? bias1 : bias2));
    float4 bv = *(const float4*)(bptr + cc);
#pragma unroll
    for (int rt = 0; rt < 4; ++rt) {
      const unsigned short* ap = As + (rt * 16 + lr) * 136 + lg * 8;
      bf16x8 a0 = *(const bf16x8*)(ap);
      bf16x8 a1 = *(const bf16x8*)(ap + 32);
      bf16x8 a2 = *(const bf16x8*)(ap + 64);
      bf16x8 a3 = *(const bf16x8*)(ap + 96);
      f32x4 acc = {0.f, 0.f, 0.f, 0.f};
      acc = __builtin_amdgcn_mfma_f32_16x16x32_bf16(b0, a0, acc, 0, 0, 0);
      acc = __builtin_amdgcn_mfma_f32_16x16x32_bf16(b1, a1, acc, 0, 0, 0);
      acc = __builtin_amdgcn_mfma_f32_16x16x32_bf16(b2, a2, acc, 0, 0, 0);
      acc = __builtin_amdgcn_mfma_f32_16x16x32_bf16(b3, a3, acc, 0, 0, 0);
      const int row = rbase + rt * 16 + lr;
      h4 o;
      o[0] = (_Float16)(acc[0] + bv.x); o[1] = (_Float16)(acc[1] + bv.y);
      o[2] = (_Float16)(acc[2] + bv.z); o[3] = (_Float16)(acc[3] + bv.w);
      _Float16* dst = (ct < 8) ? o_xl : (ct < 16 ? o_xr : o_h);
      *(h4*)(dst + (size_t)row * 128 + cc) = o;
    }
  }
}

// ---------------------------------------------------------------------------
// Merged GEMM layer 1: xl/xr outputs fp16, residual out fp32 (guarded).
// ---------------------------------------------------------------------------
__global__ __launch_bounds__(256) void gemm_l1(
    const unsigned short* __restrict__ A, const unsigned short* __restrict__ BT,
    const float* __restrict__ bias0, const float* __restrict__ bias1,
    const float* __restrict__ bias2,
    _Float16* __restrict__ o_xl, _Float16* __restrict__ o_xr,
    float* __restrict__ o_out, int M) {
  __shared__ unsigned short As[64 * 136];
  const int tid = threadIdx.x;
  const int rbase = blockIdx.x * 64;
#pragma unroll
  for (int i = 0; i < 4; ++i) {
    int c = i * 256 + tid;
    int row = c >> 4, slot = c & 15;
    int ar = rbase + row; if (ar > M - 1) ar = M - 1;
    uint4 v = *(const uint4*)(A + (size_t)ar * 128 + slot * 8);
    *(uint4*)(As + row * 136 + slot * 8) = v;
  }
  __syncthreads();
  const int w = tid >> 6, l = tid & 63;
  const int lr = l & 15, lg = l >> 4;
#pragma unroll
  for (int i = 0; i < 9; ++i) {
    const int ct = w * 9 + i;
    const bf16x8* bp = (const bf16x8*)(BT + (size_t)(ct * 16 + lr) * 128 + lg * 8);
    bf16x8 b0 = bp[0], b1 = bp[4], b2 = bp[8], b3 = bp[12];
    const int colb = ct * 16 + lg * 4;
    const int cc = (ct < 32) ? (colb & 255) : (colb - 512);
    const float* bptr = (ct < 16 ? bias0 : (ct < 32 ? bias1 : bias2));
    float4 bv = *(const float4*)(bptr + cc);
#pragma unroll
    for (int rt = 0; rt < 4; ++rt) {
      const unsigned short* ap = As + (rt * 16 + lr) * 136 + lg * 8;
      bf16x8 a0 = *(const bf16x8*)(ap);
      bf16x8 a1 = *(const bf16x8*)(ap + 32);
      bf16x8 a2 = *(const bf16x8*)(ap + 64);
      bf16x8 a3 = *(const bf16x8*)(ap + 96);
      f32x4 acc = {0.f, 0.f, 0.f, 0.f};
      acc = __builtin_amdgcn_mfma_f32_16x16x32_bf16(b0, a0, acc, 0, 0, 0);
      acc = __builtin_amdgcn_mfma_f32_16x16x32_bf16(b1, a1, acc, 0, 0, 0);
      acc = __builtin_amdgcn_mfma_f32_16x16x32_bf16(b2, a2, acc, 0, 0, 0);
      acc = __builtin_amdgcn_mfma_f32_16x16x32_bf16(b3, a3, acc, 0, 0, 0);
      const int row = rbase + rt * 16 + lr;
      if (ct < 32) {
        h4 o;
        o[0] = (_Float16)(acc[0] + bv.x); o[1] = (_Float16)(acc[1] + bv.y);
        o[2] = (_Float16)(acc[2] + bv.z); o[3] = (_Float16)(acc[3] + bv.w);
        *(h4*)((ct < 16 ? o_xl : o_xr) + (size_t)row * 256 + cc) = o;
      } else if (row < M) {
        float4 o;
        o.x = acc[0] + bv.x; o.y = acc[1] + bv.y;
        o.z = acc[2] + bv.z; o.w = acc[3] + bv.w;
        *(float4*)(o_out + (size_t)row * 64 + cc) = o;
      }
    }
  }
}

// ---------------------------------------------------------------------------
// per-edge steps, packed f16: 8 ch/lane.
// ---------------------------------------------------------------------------
__device__ inline void edge_step0(int2 rec, h8 a8, bool valid,
                                  const h2* xrv2, const h2* wef2, const h2* att2,
                                  h2* acc2, float& den) {
  _Float16 wh = (_Float16)__int_as_float(rec.y);
  h2 w2; w2[0] = wh; w2[1] = wh;
  const h2 c02 = mkh2(0.2f, 0.2f);
  int4 ai = __builtin_bit_cast(int4, a8);
  h2 av[4];
  av[0] = __builtin_bit_cast(h2, ai.x); av[1] = __builtin_bit_cast(h2, ai.y);
  av[2] = __builtin_bit_cast(h2, ai.z); av[3] = __builtin_bit_cast(h2, ai.w);
  float c = 0.f;
#pragma unroll
  for (int k = 0; k < 4; ++k) {
    h2 sv = av[k] + (w2 * wef2[k] + xrv2[k]);
    h2 lk = __builtin_elementwise_max(sv, sv * c02);
    c = hdot2(lk, att2[k], c);
  }
  c += __shfl_xor(c, 1, 64); c += __shfl_xor(c, 2, 64);   // head = 4 lanes
  float p = valid ? __expf(c) : 0.f;
  den += p;
  _Float16 ph = (_Float16)p;
  h2 p2; p2[0] = ph; p2[1] = ph;
#pragma unroll
  for (int k = 0; k < 4; ++k) acc2[k] = p2 * av[k] + acc2[k];
}

__device__ inline void edge_step1(int2 rec, h8 a8, bool valid,
                                  const h2* xrv2, const h2* wef2, const h2* att2,
                                  h2* acc2, float& den) {
  _Float16 wh = (_Float16)__int_as_float(rec.y);
  h2 w2; w2[0] = wh; w2[1] = wh;
  const h2 c02 = mkh2(0.2f, 0.2f);
  int4 ai = __builtin_bit_cast(int4, a8);
  h2 av[4];
  av[0] = __builtin_bit_cast(h2, ai.x); av[1] = __builtin_bit_cast(h2, ai.y);
  av[2] = __builtin_bit_cast(h2, ai.z); av[3] = __builtin_bit_cast(h2, ai.w);
  float c = 0.f;
#pragma unroll
  for (int k = 0; k < 4; ++k) {
    h2 sv = av[k] + (w2 * wef2[k] + xrv2[k]);
    h2 lk = __builtin_elementwise_max(sv, sv * c02);
    c = hdot2(lk, att2[k], c);
  }
  c += __shfl_xor(c, 1, 64); c += __shfl_xor(c, 2, 64); c += __shfl_xor(c, 4, 64);
  float p = valid ? __expf(c) : 0.f;
  den += p;
  _Float16 ph = (_Float16)p;
  h2 p2; p2[0] = ph; p2[1] = ph;
#pragma unroll
  for (int k = 0; k < 4; ++k) acc2[k] = p2 * av[k] + acc2[k];
}

// ---------------------------------------------------------------------------
// Layer-0 aggregation: 2 waves/block, 1 node per wave; XCD-chunked swizzle
// over 25000 blocks (= 8 * 3125); per-wave structure identical to r13.
// ---------------------------------------------------------------------------
__global__ __launch_bounds__(128) void agg0(
    const int* __restrict__ part, const int* __restrict__ bsum,
    const int* __restrict__ deg, const int2* __restrict__ csr2,
    const _Float16* __restrict__ xl, const _Float16* __restrict__ xr,
    const float* __restrict__ We, const float* __restrict__ att,
    const float* __restrict__ b, const float* __restrict__ g,
    const float* __restrict__ be, const _Float16* __restrict__ hres,
    unsigned short* __restrict__ hout) {
  const int l = threadIdx.x & 63;
  const int wv = threadIdx.x >> 6;
  const int bid = blockIdx.x;
  const int n = ((bid & 7) * 3125 + (bid >> 3)) * 2 + wv;   // XCD-chunked pairs
  const int grp = l >> 4, cl = l & 15, c0 = cl * 8;
  h2 xrv2[4], wef2[4], att2[4];
  {
    h8 x8 = *(const h8*)(xr + (size_t)n * HC0 + c0);
    int4 xi = __builtin_bit_cast(int4, x8);
    xrv2[0] = __builtin_bit_cast(h2, xi.x); xrv2[1] = __builtin_bit_cast(h2, xi.y);
    xrv2[2] = __builtin_bit_cast(h2, xi.z); xrv2[3] = __builtin_bit_cast(h2, xi.w);
    float4 w0 = *(const float4*)(We + c0),  w1 = *(const float4*)(We + c0 + 4);
    float4 t0 = *(const float4*)(att + c0), t1 = *(const float4*)(att + c0 + 4);
    wef2[0] = mkh2(w0.x, w0.y); wef2[1] = mkh2(w0.z, w0.w);
    wef2[2] = mkh2(w1.x, w1.y); wef2[3] = mkh2(w1.z, w1.w);
    att2[0] = mkh2(t0.x, t0.y); att2[1] = mkh2(t0.z, t0.w);
    att2[2] = mkh2(t1.x, t1.y); att2[3] = mkh2(t1.z, t1.w);
  }
  const int start = part[n] + bsum[n >> 8];
  const int cnt   = deg[n] + 1;
  const int2* seg = csr2 + start;
  h2 acc2[4] = {};
  float den = 0.f;
  int2 rA0 = seg[grp],      rA1 = seg[grp + 4];
  int2 rB0 = seg[grp + 8],  rB1 = seg[grp + 12];
  h8 aA0 = *(const h8*)(xl + (size_t)rA0.x * HC0 + c0);
  h8 aA1 = *(const h8*)(xl + (size_t)rA1.x * HC0 + c0);
  const int trips = (cnt + 7) >> 3;
  int e = grp;
  for (int t = 0; t < trips; ++t) {
    int2 rC0 = seg[e + 16], rC1 = seg[e + 20];
    h8 aB0 = *(const h8*)(xl + (size_t)rB0.x * HC0 + c0);
    h8 aB1 = *(const h8*)(xl + (size_t)rB1.x * HC0 + c0);
    edge_step0(rA0, aA0, e < cnt,     xrv2, wef2, att2, acc2, den);
    edge_step0(rA1, aA1, e + 4 < cnt, xrv2, wef2, att2, acc2, den);
    rA0 = rB0; rA1 = rB1; rB0 = rC0; rB1 = rC1; aA0 = aB0; aA1 = aB1;
    e += 8;
  }
  den += __shfl_xor(den, 16, 64); den += __shfl_xor(den, 32, 64);
#pragma unroll
  for (int k = 0; k < 4; ++k) {
    int b16 = __shfl_xor(__builtin_bit_cast(int, acc2[k]), 16, 64);
    acc2[k] = acc2[k] + __builtin_bit_cast(h2, b16);
    int b32 = __shfl_xor(__builtin_bit_cast(int, acc2[k]), 32, 64);
    acc2[k] = acc2[k] + __builtin_bit_cast(h2, b32);
  }
  float v[8], s1 = 0.f, s2 = 0.f;
  float dinv = 1.f / den;
  {
    float4 b0v = *(const float4*)(b + c0), b1v = *(const float4*)(b + c0 + 4);
    float bb[8] = {b0v.x,b0v.y,b0v.z,b0v.w,b1v.x,b1v.y,b1v.z,b1v.w};
#pragma unroll
    for (int j = 0; j < 8; ++j) {
      float t = (float)acc2[j >> 1][j & 1] * dinv + bb[j];
      t = t > 0.f ? t : __expf(t) - 1.f;
      v[j] = t; s1 += t; s2 += t * t;
    }
  }
  s1 += __shfl_xor(s1, 1, 64); s2 += __shfl_xor(s2, 1, 64);
  s1 += __shfl_xor(s1, 2, 64); s2 += __shfl_xor(s2, 2, 64);
  s1 += __shfl_xor(s1, 4, 64); s2 += __shfl_xor(s2, 4, 64);
  s1 += __shfl_xor(s1, 8, 64); s2 += __shfl_xor(s2, 8, 64);
  float mean = s1 * (1.f / 128.f);
  float inv  = rsqrtf(s2 * (1.f / 128.f) - mean * mean + 1e-5f);
  if (grp == 0) {
    float4 g0v = *(const float4*)(g + c0),  g1v = *(const float4*)(g + c0 + 4);
    float4 e0v = *(const float4*)(be + c0), e1v = *(const float4*)(be + c0 + 4);
    h8 hh = *(const h8*)(hres + (size_t)n * HC0 + c0);
    float gg[8] = {g0v.x,g0v.y,g0v.z,g0v.w,g1v.x,g1v.y,g1v.z,g1v.w};
    float ee[8] = {e0v.x,e0v.y,e0v.z,e0v.w,e1v.x,e1v.y,e1v.z,e1v.w};
    bf16x8 o;
#pragma unroll
    for (int j = 0; j < 8; ++j)
      o[j] = (short)f2bf((v[j] - mean) * inv * gg[j] + ee[j] + (float)hh[j]);
    *(bf16x8*)(hout + (size_t)n * HC0 + c0) = o;
  }
}

// ---------------------------------------------------------------------------
// Layer-1 aggregation: 2 waves/block, 1 node per wave; XCD-chunked swizzle;
// barrier-free epilogue (no LDS, no __syncthreads).
// ---------------------------------------------------------------------------
__global__ __launch_bounds__(128) void agg1(
    const int* __restrict__ part, const int* __restrict__ bsum,
    const int* __restrict__ deg, const int2* __restrict__ csr2,
    const _Float16* __restrict__ xl, const _Float16* __restrict__ xr,
    const float* __restrict__ We, const float* __restrict__ att,
    const float* __restrict__ b, const float* __restrict__ g,
    const float* __restrict__ be, float* __restrict__ out) {
  const int l = threadIdx.x & 63;
  const int wv = threadIdx.x >> 6;
  const int bid = blockIdx.x;
  const int n = ((bid & 7) * 3125 + (bid >> 3)) * 2 + wv;   // XCD-chunked pairs
  const int grp = l >> 5, cl = l & 31, c0 = cl * 8;
  h2 xrv2[4], wef2[4], att2[4];
  {
    h8 x8 = *(const h8*)(xr + (size_t)n * HC1 + c0);
    int4 xi = __builtin_bit_cast(int4, x8);
    xrv2[0] = __builtin_bit_cast(h2, xi.x); xrv2[1] = __builtin_bit_cast(h2, xi.y);
    xrv2[2] = __builtin_bit_cast(h2, xi.z); xrv2[3] = __builtin_bit_cast(h2, xi.w);
    float4 w0 = *(const float4*)(We + c0),  w1 = *(const float4*)(We + c0 + 4);
    float4 t0 = *(const float4*)(att + c0), t1 = *(const float4*)(att + c0 + 4);
    wef2[0] = mkh2(w0.x, w0.y); wef2[1] = mkh2(w0.z, w0.w);
    wef2[2] = mkh2(w1.x, w1.y); wef2[3] = mkh2(w1.z, w1.w);
    att2[0] = mkh2(t0.x, t0.y); att2[1] = mkh2(t0.z, t0.w);
    att2[2] = mkh2(t1.x, t1.y); att2[3] = mkh2(t1.z, t1.w);
  }
  const int start = part[n] + bsum[n >> 8];
  const int cnt   = deg[n] + 1;
  const int2* seg = csr2 + start;
  h2 acc2[4] = {};
  float den = 0.f;
  int2 rA0 = seg[grp],     rA1 = seg[grp + 2];
  int2 rB0 = seg[grp + 4], rB1 = seg[grp + 6];
  h8 aA0 = *(const h8*)(xl + (size_t)rA0.x * HC1 + c0);
  h8 aA1 = *(const h8*)(xl + (size_t)rA1.x * HC1 + c0);
  const int trips = (cnt + 3) >> 2;
  int e = grp;
  for (int t = 0; t < trips; ++t) {
    int2 rC0 = seg[e + 8], rC1 = seg[e + 10];
    h8 aB0 = *(const h8*)(xl + (size_t)rB0.x * HC1 + c0);
    h8 aB1 = *(const h8*)(xl + (size_t)rB1.x * HC1 + c0);
    edge_step1(rA0, aA0, e < cnt,     xrv2, wef2, att2, acc2, den);
    edge_step1(rA1, aA1, e + 2 < cnt, xrv2, wef2, att2, acc2, den);
    rA0 = rB0; rA1 = rB1; rB0 = rC0; rB1 = rC1; aA0 = aB0; aA1 = aB1;
    e += 4;
  }
  den += __shfl_xor(den, 32, 64);
#pragma unroll
  for (int k = 0; k < 4; ++k) {
    int b32 = __shfl_xor(__builtin_bit_cast(int, acc2[k]), 32, 64);
    acc2[k] = acc2[k] + __builtin_bit_cast(h2, b32);
  }
  // head-mean in-wave: lane cl holds head h=cl>>3, output block oc=(cl&7)*8.
  float dinv = 1.f / den;
  float v[8], s1 = 0.f, s2 = 0.f;
  const int oc = (cl & 7) * 8;
  {
    float4 b0v = *(const float4*)(b + oc), b1v = *(const float4*)(b + oc + 4);
    float bb[8] = {b0v.x,b0v.y,b0v.z,b0v.w,b1v.x,b1v.y,b1v.z,b1v.w};
#pragma unroll
    for (int j = 0; j < 8; ++j) {
      float t = (float)acc2[j >> 1][j & 1] * dinv;
      t += __shfl_xor(t, 8, 64);
      t += __shfl_xor(t, 16, 64);
      t = t * 0.25f + bb[j];
      t = t > 0.f ? t : __expf(t) - 1.f;       // ELU
      v[j] = t; s1 += t; s2 += t * t;
    }
  }
  s1 += __shfl_xor(s1, 1, 64); s2 += __shfl_xor(s2, 1, 64);
  s1 += __shfl_xor(s1, 2, 64); s2 += __shfl_xor(s2, 2, 64);
  s1 += __shfl_xor(s1, 4, 64); s2 += __shfl_xor(s2, 4, 64);
  float mean = s1 * (1.f / 64.f);
  float inv  = rsqrtf(s2 * (1.f / 64.f) - mean * mean + 1e-5f);
  if (grp == 0 && cl < 8) {
    float4 g0v = *(const float4*)(g + oc),  g1v = *(const float4*)(g + oc + 4);
    float4 e0v = *(const float4*)(be + oc), e1v = *(const float4*)(be + oc + 4);
    float gg[8] = {g0v.x,g0v.y,g0v.z,g0v.w,g1v.x,g1v.y,g1v.z,g1v.w};
    float ee[8] = {e0v.x,e0v.y,e0v.z,e0v.w,e1v.x,e1v.y,e1v.z,e1v.w};
    float* po = out + (size_t)n * 64 + oc;
    float4 o0 = *(const float4*)po, o1 = *(const float4*)(po + 4);
    o0.x += (v[0] - mean) * inv * gg[0] + ee[0];
    o0.y += (v[1] - mean) * inv * gg[1] + ee[1];
    o0.z += (v[2] - mean) * inv * gg[2] + ee[2];
    o0.w += (v[3] - mean) * inv * gg[3] + ee[3];
    o1.x += (v[4] - mean) * inv * gg[4] + ee[4];
    o1.y += (v[5] - mean) * inv * gg[5] + ee[5];
    o1.z += (v[6] - mean) * inv * gg[6] + ee[6];
    o1.w += (v[7] - mean) * inv * gg[7] + ee[7];
    *(float4*)po = o0; *(float4*)(po + 4) = o1;
  }
}

// ---------------------------------------------------------------------------
extern "C" void kernel_launch(void* const* d_in, const int* in_sizes, int n_in,
                              void* d_out, int out_size, void* d_ws, size_t ws_size,
                              hipStream_t stream) {
  const float* x    = (const float*)d_in[0];
  const int*   ei   = (const int*)  d_in[1];
  const float* ew   = (const float*)d_in[2];
  const float* Wl0  = (const float*)d_in[3];
  const float* bl0  = (const float*)d_in[4];
  const float* Wr0  = (const float*)d_in[5];
  const float* br0  = (const float*)d_in[6];
  const float* We0  = (const float*)d_in[7];
  const float* att0 = (const float*)d_in[8];
  const float* b0   = (const float*)d_in[9];
  const float* g0   = (const float*)d_in[10];
  const float* be0  = (const float*)d_in[11];
  const float* Wl1  = (const float*)d_in[12];
  const float* bl1  = (const float*)d_in[13];
  const float* Wr1  = (const float*)d_in[14];
  const float* br1  = (const float*)d_in[15];
  const float* We1  = (const float*)d_in[16];
  const float* att1 = (const float*)d_in[17];
  const float* b1   = (const float*)d_in[18];
  const float* g1   = (const float*)d_in[19];
  const float* be1  = (const float*)d_in[20];
  const float* P0   = (const float*)d_in[21];
  const float* pb0  = (const float*)d_in[22];
  const float* P1   = (const float*)d_in[23];
  const float* pb1  = (const float*)d_in[24];
  float* out = (float*)d_out;

  // workspace layout (32-bit words)
  float* f        = (float*)d_ws;
  float* s_loopw  = f;                               // 50176
  int*   deg      = (int*)(f + 50176);               // 50176
  int*   cursor   = (int*)(f + 100352);              // 50176
  int*   part     = (int*)(f + 150528);              // 50176
  int*   bsum     = (int*)(f + 200704);              // 256
  int2*  csr2     = (int2*)(f + 200960);             // 450064 int2 (incl tail)
  unsigned short* wl0T = (unsigned short*)(f + 1102080);  // 384x128 bf16
  unsigned short* wr0T = wl0T + 16384;
  unsigned short* p0T  = wl0T + 32768;
  unsigned short* wl1T = (unsigned short*)(f + 1126656);  // 576x128 bf16
  unsigned short* wr1T = wl1T + 32768;
  unsigned short* p1T  = wl1T + 65536;
  unsigned short* hb   = (unsigned short*)(f + 1163520);  // MROWS x128 bf16
  _Float16*       hres = (_Float16*)(f + 4366592);        // MROWS x128 f16
  _Float16*       RA   = (_Float16*)(f + 7569664);        // MROWS x256 f16
  _Float16*       RB   = (_Float16*)(f + 13975808);       // MROWS x256 f16
  _Float16* xl0h = RA, *xr0h = RB;
  _Float16* xl1h = RA, *xr1h = RB;

  // ---- CSR build ---------------------------------------------------------
  hipMemsetAsync(s_loopw, 0, (size_t)(50176 * 3) * sizeof(float), stream); // s,deg,cursor
  deg_kernel<<<(N_EDGES + 255) / 256, 256, 0, stream>>>(ei, ew, s_loopw, deg);
  scan1<<<NPAD / 256, 256, 0, stream>>>(deg, part, bsum);
  scan2<<<1, 256, 0, stream>>>(bsum);
  fused_build<<<EB + NB + PB, 256, 0, stream>>>(ei, ew, s_loopw, deg, part, bsum,
                                                cursor, csr2,
                                                Wl0, Wr0, P0, Wl1, Wr1, P1,
                                                wl0T, wr0T, p0T, wl1T, wr1T, p1T);

  // ---- layer 0 -----------------------------------------------------------
  const int GB = MROWS / 64;   // 782
  gemm_l0<<<GB, 256, 0, stream>>>(x, wl0T, bl0, br0, pb0, xl0h, xr0h, hres, N_NODES);
  agg0<<<N_NODES / 2, 128, 0, stream>>>(part, bsum, deg, csr2,
                                        xl0h, xr0h, We0, att0, b0, g0, be0, hres, hb);

  // ---- layer 1 -----------------------------------------------------------
  gemm_l1<<<GB, 256, 0, stream>>>(hb, wl1T, bl1, br1, pb1, xl1h, xr1h, out, N_NODES);
  agg1<<<N_NODES / 2, 128, 0, stream>>>(part, bsum, deg, csr2,
                                        xl1h, xr1h, We1, att1, b1, g1, be1, out);
}

// Round 16
// 210.024 us; speedup vs baseline: 1.0168x; 1.0168x over previous
//
#include <hip/hip_runtime.h>
#include <math.h>

#define N_NODES 50000
#define N_EDGES 400000
#define NPAD    50176            // 196*256
#define MROWS   50048            // 782*64, padded row count for gemm outputs
#define HC0 128
#define HC1 256
#define CSR_TOTAL (N_NODES + N_EDGES)   // 450000 records + 64 tail pad
#define EB 1563                  // edge blocks (1563*256 >= 400000)
#define NB 196                   // node blocks (196*256 >= 50000)
#define PB 480                   // pack blocks (480*2 = 960 BT rows-groups)

typedef short    bf16x8 __attribute__((ext_vector_type(8)));
typedef float    f32x4  __attribute__((ext_vector_type(4)));
typedef _Float16 h2     __attribute__((ext_vector_type(2)));
typedef _Float16 h4     __attribute__((ext_vector_type(4)));
typedef _Float16 h8     __attribute__((ext_vector_type(8)));

__device__ inline unsigned short f2bf(float f) {
  union { float f; unsigned u; } v; v.f = f;
  unsigned r = v.u + 0x7FFFu + ((v.u >> 16) & 1u);   // RNE
  return (unsigned short)(r >> 16);
}
__device__ inline h2 mkh2(float a, float b) {
  h2 r; r[0] = (_Float16)a; r[1] = (_Float16)b; return r;
}
__device__ inline float hdot2(h2 a, h2 b, float c) {
#if __has_builtin(__builtin_amdgcn_fdot2)
  return __builtin_amdgcn_fdot2(a, b, c, false);
#else
  return c + (float)a[0] * (float)b[0] + (float)a[1] * (float)b[1];
#endif
}

// ---------------------------------------------------------------------------
// CSR build stage 1: degree histogram + weight sums
// ---------------------------------------------------------------------------
__global__ void deg_kernel(const int* __restrict__ ei, const float* __restrict__ ew,
                           float* __restrict__ s, int* __restrict__ deg) {
  int e = blockIdx.x * 256 + threadIdx.x;
  if (e < N_EDGES) {
    int dst = ei[N_EDGES + e];
    atomicAdd(&s[dst], ew[e]);
    atomicAdd(&deg[dst], 1);
  }
}

__global__ void scan1(const int* __restrict__ deg, int* __restrict__ part,
                      int* __restrict__ bsum) {
  int i = blockIdx.x * 256 + threadIdx.x;
  int lane = threadIdx.x & 63, wid = threadIdx.x >> 6;
  int v = (i < N_NODES) ? deg[i] + 1 : 0;
  int inc = v;
#pragma unroll
  for (int d = 1; d < 64; d <<= 1) { int y = __shfl_up(inc, d, 64); if (lane >= d) inc += y; }
  __shared__ int wsum[4];
  if (lane == 63) wsum[wid] = inc;
  __syncthreads();
  int off = 0;
#pragma unroll
  for (int w = 0; w < 4; ++w) { int sv = wsum[w]; if (w < wid) off += sv; }
  part[i] = inc - v + off;
  if (threadIdx.x == 0) bsum[blockIdx.x] = wsum[0] + wsum[1] + wsum[2] + wsum[3];
}

__global__ void scan2(int* __restrict__ bsum) {
  int t = threadIdx.x;
  int lane = t & 63, wid = t >> 6;
  int v = (t < 196) ? bsum[t] : 0;
  int inc = v;
#pragma unroll
  for (int d = 1; d < 64; d <<= 1) { int y = __shfl_up(inc, d, 64); if (lane >= d) inc += y; }
  __shared__ int wsum[4];
  if (lane == 63) wsum[wid] = inc;
  __syncthreads();
  int off = 0;
#pragma unroll
  for (int w = 0; w < 4; ++w) { int sv = wsum[w]; if (w < wid) off += sv; }
  if (t < 196) bsum[t] = inc - v + off;
}

// ---------------------------------------------------------------------------
// Fused build: edge scatter | self loops + tail zero | weight pack.
// ---------------------------------------------------------------------------
__global__ void fused_build(const int* __restrict__ ei, const float* __restrict__ ew,
                            const float* __restrict__ s, const int* __restrict__ deg,
                            const int* __restrict__ part, const int* __restrict__ bsum,
                            int* __restrict__ cursor, int2* __restrict__ csr2,
                            const float* __restrict__ Wl0, const float* __restrict__ Wr0,
                            const float* __restrict__ P0,  const float* __restrict__ Wl1,
                            const float* __restrict__ Wr1, const float* __restrict__ P1,
                            unsigned short* __restrict__ o_wl0, unsigned short* __restrict__ o_wr0,
                            unsigned short* __restrict__ o_p0,  unsigned short* __restrict__ o_wl1,
                            unsigned short* __restrict__ o_wr1, unsigned short* __restrict__ o_p1) {
  const int bid = blockIdx.x;
  if (bid < EB) {                       // ---- edge scatter
    int e = bid * 256 + threadIdx.x;
    if (e >= N_EDGES) return;
    int dst = ei[N_EDGES + e];
    int pos = atomicAdd(&cursor[dst], 1);
    int idx = part[dst] + bsum[dst >> 8] + 1 + pos;
    csr2[idx] = make_int2(ei[e], __float_as_int(ew[e]));
  } else if (bid < EB + NB) {           // ---- self loops + tail zero
    int i = (bid - EB) * 256 + threadIdx.x;
    if (i < N_NODES) {
      float w = s[i] / fmaxf((float)deg[i], 1.0f);
      int start = part[i] + bsum[i >> 8];
      csr2[start] = make_int2(i, __float_as_int(w));
    } else if (i - N_NODES < 64) {
      csr2[CSR_TOTAL + (i - N_NODES)] = make_int2(0, 0);
    }
  } else {                              // ---- weight pack (2 rows/block)
    int n = (bid - EB - NB) * 2 + (threadIdx.x >> 7);
    int k = threadIdx.x & 127;
    const float* W; unsigned short* O; int N, nl;
    if      (n < 128) { W = Wl0; O = o_wl0; N = 128; nl = n; }
    else if (n < 256) { W = Wr0; O = o_wr0; N = 128; nl = n - 128; }
    else if (n < 384) { W = P0;  O = o_p0;  N = 128; nl = n - 256; }
    else if (n < 640) { W = Wl1; O = o_wl1; N = 256; nl = n - 384; }
    else if (n < 896) { W = Wr1; O = o_wr1; N = 256; nl = n - 640; }
    else              { W = P1;  O = o_p1;  N = 64;  nl = n - 896; }
    O[nl * 128 + k] = f2bf(W[(size_t)k * N + nl]);
  }
}

// ---------------------------------------------------------------------------
// Merged GEMM layer 0: reads x fp32 (stages bf16 to LDS), outputs xl/xr/hres f16.
// ---------------------------------------------------------------------------
__global__ __launch_bounds__(256) void gemm_l0(
    const float* __restrict__ X, const unsigned short* __restrict__ BT,
    const float* __restrict__ bias0, const float* __restrict__ bias1,
    const float* __restrict__ bias2,
    _Float16* __restrict__ o_xl, _Float16* __restrict__ o_xr,
    _Float16* __restrict__ o_h, int M) {
  __shared__ unsigned short As[64 * 136];   // 272B pitch
  const int tid = threadIdx.x;
  const int rbase = blockIdx.x * 64;
#pragma unroll
  for (int i = 0; i < 8; ++i) {
    int c = i * 256 + tid;
    int row = c >> 5, c4 = c & 31;
    int ar = rbase + row; if (ar > M - 1) ar = M - 1;
    float4 v = *(const float4*)(X + (size_t)ar * 128 + c4 * 4);
    ushort4 o; o.x = f2bf(v.x); o.y = f2bf(v.y); o.z = f2bf(v.z); o.w = f2bf(v.w);
    *(ushort4*)(As + row * 136 + c4 * 4) = o;
  }
  __syncthreads();
  const int w = tid >> 6, l = tid & 63;
  const int lr = l & 15, lg = l >> 4;
#pragma unroll
  for (int i = 0; i < 6; ++i) {
    const int ct = w * 6 + i;
    const bf16x8* bp = (const bf16x8*)(BT + (size_t)(ct * 16 + lr) * 128 + lg * 8);
    bf16x8 b0 = bp[0], b1 = bp[4], b2 = bp[8], b3 = bp[12];
    const int colb = ct * 16 + lg * 4;
    const int cc = colb & 127;
    const float* bptr = (ct < 8 ? bias0 : (ct < 16 ? bias1 : bias2));
    float4 bv = *(const float4*)(bptr + cc);
#pragma unroll
    for (int rt = 0; rt < 4; ++rt) {
      const unsigned short* ap = As + (rt * 16 + lr) * 136 + lg * 8;
      bf16x8 a0 = *(const bf16x8*)(ap);
      bf16x8 a1 = *(const bf16x8*)(ap + 32);
      bf16x8 a2 = *(const bf16x8*)(ap + 64);
      bf16x8 a3 = *(const bf16x8*)(ap + 96);
      f32x4 acc = {0.f, 0.f, 0.f, 0.f};
      acc = __builtin_amdgcn_mfma_f32_16x16x32_bf16(b0, a0, acc, 0, 0, 0);
      acc = __builtin_amdgcn_mfma_f32_16x16x32_bf16(b1, a1, acc, 0, 0, 0);
      acc = __builtin_amdgcn_mfma_f32_16x16x32_bf16(b2, a2, acc, 0, 0, 0);
      acc = __builtin_amdgcn_mfma_f32_16x16x32_bf16(b3, a3, acc, 0, 0, 0);
      const int row = rbase + rt * 16 + lr;
      h4 o;
      o[0] = (_Float16)(acc[0] + bv.x); o[1] = (_Float16)(acc[1] + bv.y);
      o[2] = (_Float16)(acc[2] + bv.z); o[3] = (_Float16)(acc[3] + bv.w);
      _Float16* dst = (ct < 8) ? o_xl : (ct < 16 ? o_xr : o_h);
      *(h4*)(dst + (size_t)row * 128 + cc) = o;
    }
  }
}

// ---------------------------------------------------------------------------
// Merged GEMM layer 1: xl/xr outputs fp16, residual out fp32 (guarded).
// ---------------------------------------------------------------------------
__global__ __launch_bounds__(256) void gemm_l1(
    const unsigned short* __restrict__ A, const unsigned short* __restrict__ BT,
    const float* __restrict__ bias0, const float* __restrict__ bias1,
    const float* __restrict__ bias2,
    _Float16* __restrict__ o_xl, _Float16* __restrict__ o_xr,
    float* __restrict__ o_out, int M) {
  __shared__ unsigned short As[64 * 136];
  const int tid = threadIdx.x;
  const int rbase = blockIdx.x * 64;
#pragma unroll
  for (int i = 0; i < 4; ++i) {
    int c = i * 256 + tid;
    int row = c >> 4, slot = c & 15;
    int ar = rbase + row; if (ar > M - 1) ar = M - 1;
    uint4 v = *(const uint4*)(A + (size_t)ar * 128 + slot * 8);
    *(uint4*)(As + row * 136 + slot * 8) = v;
  }
  __syncthreads();
  const int w = tid >> 6, l = tid & 63;
  const int lr = l & 15, lg = l >> 4;
#pragma unroll
  for (int i = 0; i < 9; ++i) {
    const int ct = w * 9 + i;
    const bf16x8* bp = (const bf16x8*)(BT + (size_t)(ct * 16 + lr) * 128 + lg * 8);
    bf16x8 b0 = bp[0], b1 = bp[4], b2 = bp[8], b3 = bp[12];
    const int colb = ct * 16 + lg * 4;
    const int cc = (ct < 32) ? (colb & 255) : (colb - 512);
    const float* bptr = (ct < 16 ? bias0 : (ct < 32 ? bias1 : bias2));
    float4 bv = *(const float4*)(bptr + cc);
#pragma unroll
    for (int rt = 0; rt < 4; ++rt) {
      const unsigned short* ap = As + (rt * 16 + lr) * 136 + lg * 8;
      bf16x8 a0 = *(const bf16x8*)(ap);
      bf16x8 a1 = *(const bf16x8*)(ap + 32);
      bf16x8 a2 = *(const bf16x8*)(ap + 64);
      bf16x8 a3 = *(const bf16x8*)(ap + 96);
      f32x4 acc = {0.f, 0.f, 0.f, 0.f};
      acc = __builtin_amdgcn_mfma_f32_16x16x32_bf16(b0, a0, acc, 0, 0, 0);
      acc = __builtin_amdgcn_mfma_f32_16x16x32_bf16(b1, a1, acc, 0, 0, 0);
      acc = __builtin_amdgcn_mfma_f32_16x16x32_bf16(b2, a2, acc, 0, 0, 0);
      acc = __builtin_amdgcn_mfma_f32_16x16x32_bf16(b3, a3, acc, 0, 0, 0);
      const int row = rbase + rt * 16 + lr;
      if (ct < 32) {
        h4 o;
        o[0] = (_Float16)(acc[0] + bv.x); o[1] = (_Float16)(acc[1] + bv.y);
        o[2] = (_Float16)(acc[2] + bv.z); o[3] = (_Float16)(acc[3] + bv.w);
        *(h4*)((ct < 16 ? o_xl : o_xr) + (size_t)row * 256 + cc) = o;
      } else if (row < M) {
        float4 o;
        o.x = acc[0] + bv.x; o.y = acc[1] + bv.y;
        o.z = acc[2] + bv.z; o.w = acc[3] + bv.w;
        *(float4*)(o_out + (size_t)row * 64 + cc) = o;
      }
    }
  }
}

// ---------------------------------------------------------------------------
// per-edge steps, packed f16: 8 ch/lane.
// ---------------------------------------------------------------------------
__device__ inline void edge_step0(int2 rec, h8 a8, bool valid,
                                  const h2* xrv2, const h2* wef2, const h2* att2,
                                  h2* acc2, float& den) {
  _Float16 wh = (_Float16)__int_as_float(rec.y);
  h2 w2; w2[0] = wh; w2[1] = wh;
  const h2 c02 = mkh2(0.2f, 0.2f);
  int4 ai = __builtin_bit_cast(int4, a8);
  h2 av[4];
  av[0] = __builtin_bit_cast(h2, ai.x); av[1] = __builtin_bit_cast(h2, ai.y);
  av[2] = __builtin_bit_cast(h2, ai.z); av[3] = __builtin_bit_cast(h2, ai.w);
  float c = 0.f;
#pragma unroll
  for (int k = 0; k < 4; ++k) {
    h2 sv = av[k] + (w2 * wef2[k] + xrv2[k]);
    h2 lk = __builtin_elementwise_max(sv, sv * c02);
    c = hdot2(lk, att2[k], c);
  }
  c += __shfl_xor(c, 1, 64); c += __shfl_xor(c, 2, 64);   // head = 4 lanes
  float p = valid ? __expf(c) : 0.f;
  den += p;
  _Float16 ph = (_Float16)p;
  h2 p2; p2[0] = ph; p2[1] = ph;
#pragma unroll
  for (int k = 0; k < 4; ++k) acc2[k] = p2 * av[k] + acc2[k];
}

__device__ inline void edge_step1(int2 rec, h8 a8, bool valid,
                                  const h2* xrv2, const h2* wef2, const h2* att2,
                                  h2* acc2, float& den) {
  _Float16 wh = (_Float16)__int_as_float(rec.y);
  h2 w2; w2[0] = wh; w2[1] = wh;
  const h2 c02 = mkh2(0.2f, 0.2f);
  int4 ai = __builtin_bit_cast(int4, a8);
  h2 av[4];
  av[0] = __builtin_bit_cast(h2, ai.x); av[1] = __builtin_bit_cast(h2, ai.y);
  av[2] = __builtin_bit_cast(h2, ai.z); av[3] = __builtin_bit_cast(h2, ai.w);
  float c = 0.f;
#pragma unroll
  for (int k = 0; k < 4; ++k) {
    h2 sv = av[k] + (w2 * wef2[k] + xrv2[k]);
    h2 lk = __builtin_elementwise_max(sv, sv * c02);
    c = hdot2(lk, att2[k], c);
  }
  c += __shfl_xor(c, 1, 64); c += __shfl_xor(c, 2, 64); c += __shfl_xor(c, 4, 64);
  float p = valid ? __expf(c) : 0.f;
  den += p;
  _Float16 ph = (_Float16)p;
  h2 p2; p2[0] = ph; p2[1] = ph;
#pragma unroll
  for (int k = 0; k < 4; ++k) acc2[k] = p2 * av[k] + acc2[k];
}

// ---------------------------------------------------------------------------
// Layer-0 aggregation: 1 wave/block, XCD-chunked node swizzle (50000 = 8*6250).
// ---------------------------------------------------------------------------
__global__ __launch_bounds__(64) void agg0(
    const int* __restrict__ part, const int* __restrict__ bsum,
    const int* __restrict__ deg, const int2* __restrict__ csr2,
    const _Float16* __restrict__ xl, const _Float16* __restrict__ xr,
    const float* __restrict__ We, const float* __restrict__ att,
    const float* __restrict__ b, const float* __restrict__ g,
    const float* __restrict__ be, const _Float16* __restrict__ hres,
    unsigned short* __restrict__ hout) {
  const int l = threadIdx.x & 63;
  const int bid = blockIdx.x;
  const int n = (bid & 7) * (N_NODES / 8) + (bid >> 3);   // XCD-chunked
  const int grp = l >> 4, cl = l & 15, c0 = cl * 8;
  h2 xrv2[4], wef2[4], att2[4];
  {
    h8 x8 = *(const h8*)(xr + (size_t)n * HC0 + c0);
    int4 xi = __builtin_bit_cast(int4, x8);
    xrv2[0] = __builtin_bit_cast(h2, xi.x); xrv2[1] = __builtin_bit_cast(h2, xi.y);
    xrv2[2] = __builtin_bit_cast(h2, xi.z); xrv2[3] = __builtin_bit_cast(h2, xi.w);
    float4 w0 = *(const float4*)(We + c0),  w1 = *(const float4*)(We + c0 + 4);
    float4 t0 = *(const float4*)(att + c0), t1 = *(const float4*)(att + c0 + 4);
    wef2[0] = mkh2(w0.x, w0.y); wef2[1] = mkh2(w0.z, w0.w);
    wef2[2] = mkh2(w1.x, w1.y); wef2[3] = mkh2(w1.z, w1.w);
    att2[0] = mkh2(t0.x, t0.y); att2[1] = mkh2(t0.z, t0.w);
    att2[2] = mkh2(t1.x, t1.y); att2[3] = mkh2(t1.z, t1.w);
  }
  const int start = part[n] + bsum[n >> 8];
  const int cnt   = deg[n] + 1;
  const int2* seg = csr2 + start;
  h2 acc2[4] = {};
  float den = 0.f;
  int2 rA0 = seg[grp],      rA1 = seg[grp + 4];
  int2 rB0 = seg[grp + 8],  rB1 = seg[grp + 12];
  h8 aA0 = *(const h8*)(xl + (size_t)rA0.x * HC0 + c0);
  h8 aA1 = *(const h8*)(xl + (size_t)rA1.x * HC0 + c0);
  const int trips = (cnt + 7) >> 3;
  int e = grp;
  for (int t = 0; t < trips; ++t) {
    int2 rC0 = seg[e + 16], rC1 = seg[e + 20];
    h8 aB0 = *(const h8*)(xl + (size_t)rB0.x * HC0 + c0);
    h8 aB1 = *(const h8*)(xl + (size_t)rB1.x * HC0 + c0);
    edge_step0(rA0, aA0, e < cnt,     xrv2, wef2, att2, acc2, den);
    edge_step0(rA1, aA1, e + 4 < cnt, xrv2, wef2, att2, acc2, den);
    rA0 = rB0; rA1 = rB1; rB0 = rC0; rB1 = rC1; aA0 = aB0; aA1 = aB1;
    e += 8;
  }
  den += __shfl_xor(den, 16, 64); den += __shfl_xor(den, 32, 64);
#pragma unroll
  for (int k = 0; k < 4; ++k) {
    int b16 = __shfl_xor(__builtin_bit_cast(int, acc2[k]), 16, 64);
    acc2[k] = acc2[k] + __builtin_bit_cast(h2, b16);
    int b32 = __shfl_xor(__builtin_bit_cast(int, acc2[k]), 32, 64);
    acc2[k] = acc2[k] + __builtin_bit_cast(h2, b32);
  }
  float v[8], s1 = 0.f, s2 = 0.f;
  float dinv = 1.f / den;
  {
    float4 b0v = *(const float4*)(b + c0), b1v = *(const float4*)(b + c0 + 4);
    float bb[8] = {b0v.x,b0v.y,b0v.z,b0v.w,b1v.x,b1v.y,b1v.z,b1v.w};
#pragma unroll
    for (int j = 0; j < 8; ++j) {
      float t = (float)acc2[j >> 1][j & 1] * dinv + bb[j];
      t = t > 0.f ? t : __expf(t) - 1.f;
      v[j] = t; s1 += t; s2 += t * t;
    }
  }
  s1 += __shfl_xor(s1, 1, 64); s2 += __shfl_xor(s2, 1, 64);
  s1 += __shfl_xor(s1, 2, 64); s2 += __shfl_xor(s2, 2, 64);
  s1 += __shfl_xor(s1, 4, 64); s2 += __shfl_xor(s2, 4, 64);
  s1 += __shfl_xor(s1, 8, 64); s2 += __shfl_xor(s2, 8, 64);
  float mean = s1 * (1.f / 128.f);
  float inv  = rsqrtf(s2 * (1.f / 128.f) - mean * mean + 1e-5f);
  if (grp == 0) {
    float4 g0v = *(const float4*)(g + c0),  g1v = *(const float4*)(g + c0 + 4);
    float4 e0v = *(const float4*)(be + c0), e1v = *(const float4*)(be + c0 + 4);
    h8 hh = *(const h8*)(hres + (size_t)n * HC0 + c0);
    float gg[8] = {g0v.x,g0v.y,g0v.z,g0v.w,g1v.x,g1v.y,g1v.z,g1v.w};
    float ee[8] = {e0v.x,e0v.y,e0v.z,e0v.w,e1v.x,e1v.y,e1v.z,e1v.w};
    bf16x8 o;
#pragma unroll
    for (int j = 0; j < 8; ++j)
      o[j] = (short)f2bf((v[j] - mean) * inv * gg[j] + ee[j] + (float)hh[j]);
    *(bf16x8*)(hout + (size_t)n * HC0 + c0) = o;
  }
}

// ---------------------------------------------------------------------------
// Layer-1 aggregation: 1 wave/block, XCD-chunked node swizzle; barrier-free.
// ---------------------------------------------------------------------------
__global__ __launch_bounds__(64) void agg1(
    const int* __restrict__ part, const int* __restrict__ bsum,
    const int* __restrict__ deg, const int2* __restrict__ csr2,
    const _Float16* __restrict__ xl, const _Float16* __restrict__ xr,
    const float* __restrict__ We, const float* __restrict__ att,
    const float* __restrict__ b, const float* __restrict__ g,
    const float* __restrict__ be, float* __restrict__ out) {
  const int l = threadIdx.x & 63;
  const int bid = blockIdx.x;
  const int n = (bid & 7) * (N_NODES / 8) + (bid >> 3);   // XCD-chunked
  const int grp = l >> 5, cl = l & 31, c0 = cl * 8;
  h2 xrv2[4], wef2[4], att2[4];
  {
    h8 x8 = *(const h8*)(xr + (size_t)n * HC1 + c0);
    int4 xi = __builtin_bit_cast(int4, x8);
    xrv2[0] = __builtin_bit_cast(h2, xi.x); xrv2[1] = __builtin_bit_cast(h2, xi.y);
    xrv2[2] = __builtin_bit_cast(h2, xi.z); xrv2[3] = __builtin_bit_cast(h2, xi.w);
    float4 w0 = *(const float4*)(We + c0),  w1 = *(const float4*)(We + c0 + 4);
    float4 t0 = *(const float4*)(att + c0), t1 = *(const float4*)(att + c0 + 4);
    wef2[0] = mkh2(w0.x, w0.y); wef2[1] = mkh2(w0.z, w0.w);
    wef2[2] = mkh2(w1.x, w1.y); wef2[3] = mkh2(w1.z, w1.w);
    att2[0] = mkh2(t0.x, t0.y); att2[1] = mkh2(t0.z, t0.w);
    att2[2] = mkh2(t1.x, t1.y); att2[3] = mkh2(t1.z, t1.w);
  }
  const int start = part[n] + bsum[n >> 8];
  const int cnt   = deg[n] + 1;
  const int2* seg = csr2 + start;
  h2 acc2[4] = {};
  float den = 0.f;
  int2 rA0 = seg[grp],     rA1 = seg[grp + 2];
  int2 rB0 = seg[grp + 4], rB1 = seg[grp + 6];
  h8 aA0 = *(const h8*)(xl + (size_t)rA0.x * HC1 + c0);
  h8 aA1 = *(const h8*)(xl + (size_t)rA1.x * HC1 + c0);
  const int trips = (cnt + 3) >> 2;
  int e = grp;
  for (int t = 0; t < trips; ++t) {
    int2 rC0 = seg[e + 8], rC1 = seg[e + 10];
    h8 aB0 = *(const h8*)(xl + (size_t)rB0.x * HC1 + c0);
    h8 aB1 = *(const h8*)(xl + (size_t)rB1.x * HC1 + c0);
    edge_step1(rA0, aA0, e < cnt,     xrv2, wef2, att2, acc2, den);
    edge_step1(rA1, aA1, e + 2 < cnt, xrv2, wef2, att2, acc2, den);
    rA0 = rB0; rA1 = rB1; rB0 = rC0; rB1 = rC1; aA0 = aB0; aA1 = aB1;
    e += 4;
  }
  den += __shfl_xor(den, 32, 64);
#pragma unroll
  for (int k = 0; k < 4; ++k) {
    int b32 = __shfl_xor(__builtin_bit_cast(int, acc2[k]), 32, 64);
    acc2[k] = acc2[k] + __builtin_bit_cast(h2, b32);
  }
  // head-mean in-wave: lane cl holds head h=cl>>3, output block oc=(cl&7)*8.
  float dinv = 1.f / den;
  float v[8], s1 = 0.f, s2 = 0.f;
  const int oc = (cl & 7) * 8;
  {
    float4 b0v = *(const float4*)(b + oc), b1v = *(const float4*)(b + oc + 4);
    float bb[8] = {b0v.x,b0v.y,b0v.z,b0v.w,b1v.x,b1v.y,b1v.z,b1v.w};
#pragma unroll
    for (int j = 0; j < 8; ++j) {
      float t = (float)acc2[j >> 1][j & 1] * dinv;
      t += __shfl_xor(t, 8, 64);
      t += __shfl_xor(t, 16, 64);
      t = t * 0.25f + bb[j];
      t = t > 0.f ? t : __expf(t) - 1.f;       // ELU
      v[j] = t; s1 += t; s2 += t * t;
    }
  }
  s1 += __shfl_xor(s1, 1, 64); s2 += __shfl_xor(s2, 1, 64);
  s1 += __shfl_xor(s1, 2, 64); s2 += __shfl_xor(s2, 2, 64);
  s1 += __shfl_xor(s1, 4, 64); s2 += __shfl_xor(s2, 4, 64);
  float mean = s1 * (1.f / 64.f);
  float inv  = rsqrtf(s2 * (1.f / 64.f) - mean * mean + 1e-5f);
  if (grp == 0 && cl < 8) {
    float4 g0v = *(const float4*)(g + oc),  g1v = *(const float4*)(g + oc + 4);
    float4 e0v = *(const float4*)(be + oc), e1v = *(const float4*)(be + oc + 4);
    float gg[8] = {g0v.x,g0v.y,g0v.z,g0v.w,g1v.x,g1v.y,g1v.z,g1v.w};
    float ee[8] = {e0v.x,e0v.y,e0v.z,e0v.w,e1v.x,e1v.y,e1v.z,e1v.w};
    float* po = out + (size_t)n * 64 + oc;
    float4 o0 = *(const float4*)po, o1 = *(const float4*)(po + 4);
    o0.x += (v[0] - mean) * inv * gg[0] + ee[0];
    o0.y += (v[1] - mean) * inv * gg[1] + ee[1];
    o0.z += (v[2] - mean) * inv * gg[2] + ee[2];
    o0.w += (v[3] - mean) * inv * gg[3] + ee[3];
    o1.x += (v[4] - mean) * inv * gg[4] + ee[4];
    o1.y += (v[5] - mean) * inv * gg[5] + ee[5];
    o1.z += (v[6] - mean) * inv * gg[6] + ee[6];
    o1.w += (v[7] - mean) * inv * gg[7] + ee[7];
    *(float4*)po = o0; *(float4*)(po + 4) = o1;
  }
}

// ---------------------------------------------------------------------------
extern "C" void kernel_launch(void* const* d_in, const int* in_sizes, int n_in,
                              void* d_out, int out_size, void* d_ws, size_t ws_size,
                              hipStream_t stream) {
  const float* x    = (const float*)d_in[0];
  const int*   ei   = (const int*)  d_in[1];
  const float* ew   = (const float*)d_in[2];
  const float* Wl0  = (const float*)d_in[3];
  const float* bl0  = (const float*)d_in[4];
  const float* Wr0  = (const float*)d_in[5];
  const float* br0  = (const float*)d_in[6];
  const float* We0  = (const float*)d_in[7];
  const float* att0 = (const float*)d_in[8];
  const float* b0   = (const float*)d_in[9];
  const float* g0   = (const float*)d_in[10];
  const float* be0  = (const float*)d_in[11];
  const float* Wl1  = (const float*)d_in[12];
  const float* bl1  = (const float*)d_in[13];
  const float* Wr1  = (const float*)d_in[14];
  const float* br1  = (const float*)d_in[15];
  const float* We1  = (const float*)d_in[16];
  const float* att1 = (const float*)d_in[17];
  const float* b1   = (const float*)d_in[18];
  const float* g1   = (const float*)d_in[19];
  const float* be1  = (const float*)d_in[20];
  const float* P0   = (const float*)d_in[21];
  const float* pb0  = (const float*)d_in[22];
  const float* P1   = (const float*)d_in[23];
  const float* pb1  = (const float*)d_in[24];
  float* out = (float*)d_out;

  // workspace layout (32-bit words)
  float* f        = (float*)d_ws;
  float* s_loopw  = f;                               // 50176
  int*   deg      = (int*)(f + 50176);               // 50176
  int*   cursor   = (int*)(f + 100352);              // 50176
  int*   part     = (int*)(f + 150528);              // 50176
  int*   bsum     = (int*)(f + 200704);              // 256
  int2*  csr2     = (int2*)(f + 200960);             // 450064 int2 (incl tail)
  unsigned short* wl0T = (unsigned short*)(f + 1102080);  // 384x128 bf16
  unsigned short* wr0T = wl0T + 16384;
  unsigned short* p0T  = wl0T + 32768;
  unsigned short* wl1T = (unsigned short*)(f + 1126656);  // 576x128 bf16
  unsigned short* wr1T = wl1T + 32768;
  unsigned short* p1T  = wl1T + 65536;
  unsigned short* hb   = (unsigned short*)(f + 1163520);  // MROWS x128 bf16
  _Float16*       hres = (_Float16*)(f + 4366592);        // MROWS x128 f16
  _Float16*       RA   = (_Float16*)(f + 7569664);        // MROWS x256 f16
  _Float16*       RB   = (_Float16*)(f + 13975808);       // MROWS x256 f16
  _Float16* xl0h = RA, *xr0h = RB;
  _Float16* xl1h = RA, *xr1h = RB;

  // ---- CSR build ---------------------------------------------------------
  hipMemsetAsync(s_loopw, 0, (size_t)(50176 * 3) * sizeof(float), stream); // s,deg,cursor
  deg_kernel<<<(N_EDGES + 255) / 256, 256, 0, stream>>>(ei, ew, s_loopw, deg);
  scan1<<<NPAD / 256, 256, 0, stream>>>(deg, part, bsum);
  scan2<<<1, 256, 0, stream>>>(bsum);
  fused_build<<<EB + NB + PB, 256, 0, stream>>>(ei, ew, s_loopw, deg, part, bsum,
                                                cursor, csr2,
                                                Wl0, Wr0, P0, Wl1, Wr1, P1,
                                                wl0T, wr0T, p0T, wl1T, wr1T, p1T);

  // ---- layer 0 -----------------------------------------------------------
  const int GB = MROWS / 64;   // 782
  gemm_l0<<<GB, 256, 0, stream>>>(x, wl0T, bl0, br0, pb0, xl0h, xr0h, hres, N_NODES);
  agg0<<<N_NODES, 64, 0, stream>>>(part, bsum, deg, csr2,
                                   xl0h, xr0h, We0, att0, b0, g0, be0, hres, hb);

  // ---- layer 1 -----------------------------------------------------------
  gemm_l1<<<GB, 256, 0, stream>>>(hb, wl1T, bl1, br1, pb1, xl1h, xr1h, out, N_NODES);
  agg1<<<N_NODES, 64, 0, stream>>>(part, bsum, deg, csr2,
                                   xl1h, xr1h, We1, att1, b1, g1, be1, out);
}